// Round 2
// baseline (550.433 us; speedup 1.0000x reference)
//
#include <hip/hip_runtime.h>
#include <hip/hip_bf16.h>

#define N_NODES 50000
#define N_EDGES 800000
#define SCAN_BLOCK 512
#define SCAN_GRID 98   // ceil(50000/512)

typedef __hip_bfloat16 bf16;

// ---------- helpers ----------
__device__ __forceinline__ void store_g(float* p, float v) { *p = v; }
__device__ __forceinline__ void store_g(bf16* p, float v) { *p = __float2bfloat16(v); }
__device__ __forceinline__ float bf_lo(unsigned u) { union { unsigned i; float f; } c; c.i = u << 16; return c.f; }
__device__ __forceinline__ float bf_hi(unsigned u) { union { unsigned i; float f; } c; c.i = u & 0xffff0000u; return c.f; }

// ---------- 0. precompute -0.5/(sigma^2+eps) ----------
__global__ void prep_c1_kernel(const float* __restrict__ sigma, float* __restrict__ c1) {
    int i = threadIdx.x;
    if (i < 24) {
        float s = sigma[i];
        c1[i] = -0.5f / (s * s + 1e-15f);
    }
}

// ---------- 1. x_trans = x @ W_g, stored bf16 interleaved [node][m(64)][k(8)] ----------
__global__ void gemm_xt_kernel(const float* __restrict__ x, const float* __restrict__ Wg,
                               bf16* __restrict__ xt) {
    __shared__ float xs[16][64];
    const int tid = threadIdx.x;
    const int row0 = blockIdx.x << 4;
    for (int i = tid; i < 1024; i += 256) xs[i >> 6][i & 63] = x[(size_t)row0 * 64 + i];
    __syncthreads();

    float acc0[16], acc1[16];
#pragma unroll
    for (int r = 0; r < 16; r++) { acc0[r] = 0.f; acc1[r] = 0.f; }

#pragma unroll 4
    for (int i = 0; i < 64; i++) {
        float w0 = Wg[i * 512 + tid];
        float w1 = Wg[i * 512 + tid + 256];
#pragma unroll
        for (int r = 0; r < 16; r++) {
            float xv = xs[r][i];
            acc0[r] = fmaf(xv, w0, acc0[r]);
            acc1[r] = fmaf(xv, w1, acc1[r]);
        }
    }
    // col = tid -> (k = tid>>6, m = tid&63); col = tid+256 -> (k+4, m)
    const int m = tid & 63, k0 = tid >> 6;
#pragma unroll
    for (int r = 0; r < 16; r++) {
        size_t base = ((size_t)(row0 + r)) * 512 + m * 8 + k0;
        xt[base] = __float2bfloat16(acc0[r]);
        xt[base + 4] = __float2bfloat16(acc1[r]);
    }
}

// ---------- 2a. degree histograms ----------
__global__ void hist_kernel(const int* __restrict__ eidx, int* __restrict__ deg_src,
                            int* __restrict__ indeg) {
    const int e = blockIdx.x * 256 + threadIdx.x;
    if (e < N_EDGES) {
        atomicAdd(&deg_src[eidx[e]], 1);
        atomicAdd(&indeg[eidx[N_EDGES + e]], 1);
    }
}

// ---------- 2b. exclusive scan over src degrees ----------
__global__ void scan1_kernel(const int* __restrict__ deg, int* __restrict__ excl,
                             int* __restrict__ bsum) {
    __shared__ int sd[SCAN_BLOCK];
    const int tid = threadIdx.x;
    const int i = blockIdx.x * SCAN_BLOCK + tid;
    const int v = (i < N_NODES) ? deg[i] : 0;
    sd[tid] = v;
    for (int off = 1; off < SCAN_BLOCK; off <<= 1) {
        __syncthreads();
        const int t = (tid >= off) ? sd[tid - off] : 0;
        __syncthreads();
        sd[tid] += t;
    }
    if (i < N_NODES) excl[i] = sd[tid] - v;
    if (tid == SCAN_BLOCK - 1) bsum[blockIdx.x] = sd[tid];
}

__global__ void scan2_kernel(const int* __restrict__ bsum, int* __restrict__ boff,
                             int* __restrict__ starts) {
    if (threadIdx.x == 0) {
        int acc = 0;
        for (int b = 0; b < SCAN_GRID; ++b) { boff[b] = acc; acc += bsum[b]; }
        starts[N_NODES] = acc;   // == N_EDGES
    }
}

__global__ void scan3_kernel(const int* __restrict__ excl, const int* __restrict__ boff,
                             int* __restrict__ starts, int* __restrict__ cursor) {
    const int i = blockIdx.x * SCAN_BLOCK + threadIdx.x;
    if (i < N_NODES) {
        const int s = excl[i] + boff[blockIdx.x];
        starts[i] = s;
        cursor[i] = s;
    }
}

// ---------- 2c. build src-sorted edge arrays: gauss (deg-normalized) + dst ----------
template <typename GT>
__global__ void build_kernel(const int* __restrict__ eidx, const float* __restrict__ eattr,
                             const float* __restrict__ mu, const float* __restrict__ c1,
                             const int* __restrict__ indeg, int* __restrict__ cursor,
                             int* __restrict__ gdst, GT* __restrict__ gw) {
    __shared__ float smu[24], sc1[24];
    const int tid = threadIdx.x;
    if (tid < 24) smu[tid] = mu[tid];
    else if (tid < 48) sc1[tid - 24] = c1[tid - 24];
    __syncthreads();

    const int e = blockIdx.x * 256 + tid;
    if (e >= N_EDGES) return;
    const int src = eidx[e];
    const int dst = eidx[N_EDGES + e];
    const float a0 = eattr[3 * e + 0];
    const float a1 = eattr[3 * e + 1];
    const float a2 = eattr[3 * e + 2];
    const int dg = indeg[dst];
    const float inv = 1.0f / (float)(dg > 1 ? dg : 1);

    const int pos = atomicAdd(&cursor[src], 1);
    gdst[pos] = dst;
    GT* gp = gw + (size_t)pos * 8;
#pragma unroll
    for (int k = 0; k < 8; k++) {
        const float d0 = a0 - smu[3 * k + 0];
        const float d1 = a1 - smu[3 * k + 1];
        const float d2 = a2 - smu[3 * k + 2];
        const float g = __expf(fmaf(d0 * d0, sc1[3 * k + 0],
                               fmaf(d1 * d1, sc1[3 * k + 1],
                                    d2 * d2 * sc1[3 * k + 2])));
        store_g(&gp[k], g * inv);
    }
}

// ---------- 2d. CSR pass: one wave per src node ----------
template <typename GT>
__global__ void __launch_bounds__(256) csr_kernel(const int* __restrict__ starts,
                                                  const int* __restrict__ gdst,
                                                  const GT* __restrict__ gw,
                                                  const bf16* __restrict__ xt,
                                                  float* __restrict__ agg) {
    const int wid = (blockIdx.x << 2) + (threadIdx.x >> 6);
    const int lane = threadIdx.x & 63;
    if (wid >= N_NODES) return;
    const int s0 = starts[wid], s1 = starts[wid + 1];
    if (s0 >= s1) return;

    // coalesced 16B/lane load of this node's x_trans row (interleaved layout)
    const int4 q = *(const int4*)(xt + (size_t)wid * 512 + lane * 8);
    float xv[8];
    xv[0] = bf_lo(q.x); xv[1] = bf_hi(q.x);
    xv[2] = bf_lo(q.y); xv[3] = bf_hi(q.y);
    xv[4] = bf_lo(q.z); xv[5] = bf_hi(q.z);
    xv[6] = bf_lo(q.w); xv[7] = bf_hi(q.w);

    for (int j = s0; j < s1; ++j) {
        const int dst = gdst[j];
        float g[8];
        if constexpr (sizeof(GT) == 4) {
            const float4 g0 = *(const float4*)(gw + (size_t)j * 8);
            const float4 g1 = *(const float4*)(gw + (size_t)j * 8 + 4);
            g[0] = g0.x; g[1] = g0.y; g[2] = g0.z; g[3] = g0.w;
            g[4] = g1.x; g[5] = g1.y; g[6] = g1.z; g[7] = g1.w;
        } else {
            const int4 gq = *(const int4*)(gw + (size_t)j * 8);
            g[0] = bf_lo(gq.x); g[1] = bf_hi(gq.x);
            g[2] = bf_lo(gq.y); g[3] = bf_hi(gq.y);
            g[4] = bf_lo(gq.z); g[5] = bf_hi(gq.z);
            g[6] = bf_lo(gq.w); g[7] = bf_hi(gq.w);
        }
        float v = 0.f;
#pragma unroll
        for (int k = 0; k < 8; k++) v = fmaf(g[k], xv[k], v);
        atomicAdd(&agg[(size_t)dst * 64 + lane], v);
    }
}

// ---------- fallback (small ws): direct edge kernel + divide ----------
__global__ void edge_fallback_kernel(const int* __restrict__ eidx, const float* __restrict__ eattr,
                                     const float* __restrict__ mu, const float* __restrict__ c1,
                                     const bf16* __restrict__ xt, float* __restrict__ agg,
                                     float* __restrict__ cnt) {
    __shared__ float smu[24], sc1[24];
    const int tid = threadIdx.x;
    if (tid < 24) smu[tid] = mu[tid];
    else if (tid < 48) sc1[tid - 24] = c1[tid - 24];
    __syncthreads();

    const int e = (blockIdx.x << 2) + (tid >> 6);
    const int lane = tid & 63;
    const int src = eidx[e];
    const int dst = eidx[N_EDGES + e];
    const float a0 = eattr[e * 3 + 0];
    const float a1 = eattr[e * 3 + 1];
    const float a2 = eattr[e * 3 + 2];

    const int kk = lane & 7;
    const float d0 = a0 - smu[kk * 3 + 0];
    const float d1 = a1 - smu[kk * 3 + 1];
    const float d2 = a2 - smu[kk * 3 + 2];
    const float gv = __expf(fmaf(d0 * d0, sc1[kk * 3 + 0],
                            fmaf(d1 * d1, sc1[kk * 3 + 1],
                                 d2 * d2 * sc1[kk * 3 + 2])));

    const int4 q = *(const int4*)(xt + (size_t)src * 512 + lane * 8);
    float xv[8];
    xv[0] = bf_lo(q.x); xv[1] = bf_hi(q.x);
    xv[2] = bf_lo(q.y); xv[3] = bf_hi(q.y);
    xv[4] = bf_lo(q.z); xv[5] = bf_hi(q.z);
    xv[6] = bf_lo(q.w); xv[7] = bf_hi(q.w);

    float v = 0.f;
#pragma unroll
    for (int k = 0; k < 8; k++) {
        float gk = __shfl(gv, k, 64);
        v = fmaf(gk, xv[k], v);
    }
    atomicAdd(&agg[(size_t)dst * 64 + lane], v);
    if (lane == 0) atomicAdd(&cnt[dst], 1.0f);
}

__global__ void divide_kernel(float* __restrict__ agg, const float* __restrict__ cnt) {
    const int i = blockIdx.x * 256 + threadIdx.x;
    agg[i] /= fmaxf(cnt[i >> 6], 1.0f);
}

// ---------- 3. root GEMM + bias + BN stat partials (LDS-tiled) ----------
__global__ void root_stats_kernel(const float* __restrict__ x, const float* __restrict__ Wr,
                                  const float* __restrict__ bias, const float* __restrict__ agg,
                                  float* __restrict__ out,
                                  double* __restrict__ colsum, double* __restrict__ colsumsq) {
    __shared__ float wr[4096];
    __shared__ float xs[16][64];
    __shared__ float rs[256], rsq[256];
    const int tid = threadIdx.x;
    for (int i = tid; i < 4096; i += 256) wr[i] = Wr[i];
    const int row0 = blockIdx.x << 4;
    for (int i = tid; i < 1024; i += 256) xs[i >> 6][i & 63] = x[(size_t)row0 * 64 + i];
    __syncthreads();

    const int col = tid & 63, rg = tid >> 6;
    const float b = bias[col];
    float s = 0.f, sq = 0.f;
#pragma unroll
    for (int rr = 0; rr < 4; rr++) {
        const int r = rg * 4 + rr;
        float acc = 0.f;
#pragma unroll
        for (int i = 0; i < 64; i++) acc = fmaf(xs[r][i], wr[i * 64 + col], acc);
        const size_t o = (size_t)(row0 + r) * 64 + col;
        const float val = agg[o] + acc + b;
        out[o] = val;
        s += val;
        sq += val * val;
    }
    rs[tid] = s; rsq[tid] = sq;
    __syncthreads();
    if (tid < 64) {
        const float ts = rs[tid] + rs[tid + 64] + rs[tid + 128] + rs[tid + 192];
        const float tq = rsq[tid] + rsq[tid + 64] + rsq[tid + 128] + rsq[tid + 192];
        atomicAdd(&colsum[tid], (double)ts);
        atomicAdd(&colsumsq[tid], (double)tq);
    }
}

// ---------- 4. finalize BN params ----------
__global__ void bn_prep_kernel(const double* __restrict__ colsum, const double* __restrict__ colsumsq,
                               float* __restrict__ meanr) {
    const int c = threadIdx.x;
    if (c < 64) {
        const double m = colsum[c] / (double)N_NODES;
        const double var = colsumsq[c] / (double)N_NODES - m * m;
        meanr[c] = (float)m;
        meanr[64 + c] = (float)(1.0 / sqrt(var + 1e-5));
    }
}

// ---------- 5. BN apply + LeakyReLU ----------
__global__ void finalize_kernel(float* __restrict__ out, const float* __restrict__ meanr,
                                const float* __restrict__ gamma, const float* __restrict__ beta) {
    const int i = blockIdx.x * 256 + threadIdx.x;
    const int c = i & 63;
    const float v = out[i];
    const float o = fmaf((v - meanr[c]) * meanr[64 + c], gamma[c], beta[c]);
    out[i] = o > 0.f ? o : 0.01f * o;
}

extern "C" void kernel_launch(void* const* d_in, const int* in_sizes, int n_in,
                              void* d_out, int out_size, void* d_ws, size_t ws_size,
                              hipStream_t stream) {
    const float* x     = (const float*)d_in[0];
    const int*   eidx  = (const int*)d_in[1];
    const float* eattr = (const float*)d_in[2];
    const float* Wg    = (const float*)d_in[3];
    const float* mu    = (const float*)d_in[4];
    const float* sigma = (const float*)d_in[5];
    const float* Wr    = (const float*)d_in[6];
    const float* bias  = (const float*)d_in[7];
    const float* gamma = (const float*)d_in[8];
    const float* beta  = (const float*)d_in[9];
    float* out = (float*)d_out;

    char* ws = (char*)d_ws;
    // layout (bytes)
    const size_t agg_off      = 0;                         // 12,800,000  [zeroed]
    const size_t indeg_off    = 12800000;                  // 200,000     [zeroed] (cnt float in fallback)
    const size_t degsrc_off   = 13000000;                  // 200,000     [zeroed]
    const size_t colsum_off   = 13200000;                  // 512         [zeroed]
    const size_t colsumsq_off = 13200512;                  // 512         [zeroed]
    const size_t zero_bytes   = 13201024;
    const size_t meanr_off    = 13201024;                  // 512
    const size_t c1_off       = 13201536;                  // 128
    const size_t excl_off     = 13201664;                  // 200,000
    const size_t bsum_off     = 13401664;                  // 512
    const size_t boff_off     = 13402176;                  // 512
    const size_t starts_off   = 13402688;                  // 200,064
    const size_t cursor_off   = 13602752;                  // 200,000
    const size_t gdst_off     = 13802752;                  // 3,200,000
    const size_t gw_off       = 17002752;                  // 25.6MB f32 or 12.8MB bf16
    const size_t planA_xt_off = gw_off + (size_t)N_EDGES * 8 * 4;
    const size_t planB_xt_off = gw_off + (size_t)N_EDGES * 8 * 2;
    const size_t fb_xt_off    = 13201664;                  // fallback: xt right after c1
    const size_t xt_bytes     = (size_t)N_NODES * 512 * 2;

    float*  agg      = (float*)(ws + agg_off);
    int*    indeg    = (int*)(ws + indeg_off);
    float*  cnt      = (float*)(ws + indeg_off);
    int*    deg_src  = (int*)(ws + degsrc_off);
    double* colsum   = (double*)(ws + colsum_off);
    double* colsumsq = (double*)(ws + colsumsq_off);
    float*  meanr    = (float*)(ws + meanr_off);
    float*  c1       = (float*)(ws + c1_off);
    int*    excl     = (int*)(ws + excl_off);
    int*    bsum     = (int*)(ws + bsum_off);
    int*    boff     = (int*)(ws + boff_off);
    int*    starts   = (int*)(ws + starts_off);
    int*    cursor   = (int*)(ws + cursor_off);
    int*    gdst     = (int*)(ws + gdst_off);

    hipMemsetAsync(ws + agg_off, 0, zero_bytes, stream);
    prep_c1_kernel<<<1, 32, 0, stream>>>(sigma, c1);

    const bool planA = ws_size >= planA_xt_off + xt_bytes;
    const bool planB = !planA && ws_size >= planB_xt_off + xt_bytes;

    if (planA || planB) {
        bf16* xt = (bf16*)(ws + (planA ? planA_xt_off : planB_xt_off));
        gemm_xt_kernel<<<N_NODES / 16, 256, 0, stream>>>(x, Wg, xt);
        hist_kernel<<<N_EDGES / 256, 256, 0, stream>>>(eidx, deg_src, indeg);
        scan1_kernel<<<SCAN_GRID, SCAN_BLOCK, 0, stream>>>(deg_src, excl, bsum);
        scan2_kernel<<<1, 64, 0, stream>>>(bsum, boff, starts);
        scan3_kernel<<<SCAN_GRID, SCAN_BLOCK, 0, stream>>>(excl, boff, starts, cursor);
        if (planA) {
            float* gw = (float*)(ws + gw_off);
            build_kernel<float><<<N_EDGES / 256, 256, 0, stream>>>(eidx, eattr, mu, c1, indeg, cursor, gdst, gw);
            csr_kernel<float><<<N_NODES / 4, 256, 0, stream>>>(starts, gdst, gw, xt, agg);
        } else {
            bf16* gw = (bf16*)(ws + gw_off);
            build_kernel<bf16><<<N_EDGES / 256, 256, 0, stream>>>(eidx, eattr, mu, c1, indeg, cursor, gdst, gw);
            csr_kernel<bf16><<<N_NODES / 4, 256, 0, stream>>>(starts, gdst, gw, xt, agg);
        }
    } else {
        bf16* xt = (bf16*)(ws + fb_xt_off);
        gemm_xt_kernel<<<N_NODES / 16, 256, 0, stream>>>(x, Wg, xt);
        edge_fallback_kernel<<<N_EDGES / 4, 256, 0, stream>>>(eidx, eattr, mu, c1, xt, agg, cnt);
        divide_kernel<<<(N_NODES * 64) / 256, 256, 0, stream>>>(agg, cnt);
    }

    root_stats_kernel<<<N_NODES / 16, 256, 0, stream>>>(x, Wr, bias, agg, out, colsum, colsumsq);
    bn_prep_kernel<<<1, 64, 0, stream>>>(colsum, colsumsq, meanr);
    finalize_kernel<<<(N_NODES * 64) / 256, 256, 0, stream>>>(out, meanr, gamma, beta);
}